// Round 3
// baseline (439.306 us; speedup 1.0000x reference)
//
#include <hip/hip_runtime.h>
#include <math.h>

#define N_NODES 50000
#define N_EDGES 1600000
#define D_IN 128
#define D_OUT 32
#define ALPHA 0.2f

#define NB  512      // buckets
#define RPB 98       // rows per bucket (512*98 = 50176 >= 50000)
#define CAP 4096     // slots per bucket region (mean 3125, sigma ~56 -> 17 sigma)
#define PT  16       // edges per thread in k_part
#define PB  512      // threads per block in k_part
#define EB  (PT * PB) // 8192 edges per block

// Monotone float<->int key (involution). Works with signed atomicMin/Max.
__device__ __forceinline__ int enc_f(float x) {
    int i = __float_as_int(x);
    return i >= 0 ? i : (i ^ 0x7fffffff);
}
__device__ __forceinline__ float dec_f(int k) {
    return __int_as_float(k >= 0 ? k : (k ^ 0x7fffffff));
}

// Kernel A: X_prime = X @ W  [N,32], s0 = Xp.a0, s1 = Xp.a1.
// 8 nodes per 256-thread block; 32 lanes per node (one per output dim).
// Block 0 also zeroes the bucket counters + minmax slots (stream-ordered).
__global__ __launch_bounds__(256) void k_xw(const float* __restrict__ X,
                                            const float* __restrict__ W,
                                            const float* __restrict__ a0,
                                            const float* __restrict__ a1,
                                            float* __restrict__ Xp,
                                            float* __restrict__ s0,
                                            float* __restrict__ s1,
                                            int* __restrict__ minmax,
                                            int* __restrict__ gcount) {
    __shared__ float Wl[D_IN * D_OUT]; // 16 KiB
    __shared__ float Xl[8 * D_IN];     // 4 KiB
    const int tid = threadIdx.x;
    if (blockIdx.x == 0) {
        if (tid == 0) {
            minmax[0] = 0x7fffffff; // running min key
            minmax[1] = 0x80000000; // running max key
        }
        for (int i = tid; i < NB; i += 256) gcount[i] = 0;
    }
    for (int i = tid; i < D_IN * D_OUT; i += 256) Wl[i] = W[i];
    const int node0 = blockIdx.x * 8; // 50000/8 = 6250 blocks, no tail
    for (int i = tid; i < 8 * D_IN; i += 256) Xl[i] = X[(size_t)node0 * D_IN + i];
    __syncthreads();

    const int g = tid >> 5;   // node group within block
    const int t = tid & 31;   // output dim
    const int node = node0 + g;
    const float* xr = &Xl[g * D_IN];
    float acc = 0.f;
#pragma unroll
    for (int k = 0; k < D_IN; ++k) acc += xr[k] * Wl[k * D_OUT + t];
    Xp[(size_t)node * D_OUT + t] = acc;

    float v0 = acc * a0[t];
    float v1 = acc * a1[t];
#pragma unroll
    for (int m = 16; m >= 1; m >>= 1) {
        v0 += __shfl_xor(v0, m);
        v1 += __shfl_xor(v1, m);
    }
    if (t == 0) { s0[node] = v0; s1[node] = v1; }
}

// Kernel B: bucket-partition edges + global min/max.
// Per block: LDS histogram over NB buckets -> one global atomicAdd per
// bucket reserves a contiguous range in that bucket's fixed region ->
// packed 4B entries written in per-block bursts (line-batched, one XCD).
__global__ __launch_bounds__(PB) void k_part(const int* __restrict__ row,
                                             const int* __restrict__ col,
                                             const float* __restrict__ s0,
                                             const float* __restrict__ s1,
                                             int* __restrict__ gcount,
                                             int* __restrict__ minmax,
                                             unsigned* __restrict__ gEdges) {
    __shared__ int hist[NB];
    __shared__ int lcur[NB];
    __shared__ int smn[PB / 64], smx[PB / 64];
    const int t = threadIdx.x;
    for (int i = t; i < NB; i += PB) hist[i] = 0;
    __syncthreads();

    const int base = blockIdx.x * EB;
    unsigned pa[PT];
    int cnt = 0;
    int kmin = 0x7fffffff, kmax = 0x80000000;
#pragma unroll
    for (int i = 0; i < PT; ++i) {
        const int e = base + i * PB + t;
        if (e >= N_EDGES) break; // e increases with i
        const int r = row[e];
        const int c = col[e];
        float a = s0[r] + s1[c];
        a = a > 0.f ? a : ALPHA * a;
        const int k = enc_f(a);
        kmin = min(kmin, k);
        kmax = max(kmax, k);
        const unsigned b = (unsigned)r / RPB;
        const unsigned lr = (unsigned)r - b * RPB;
        pa[cnt++] = (b << 23) | (lr << 16) | (unsigned)c;
        atomicAdd(&hist[b], 1);
    }
    __syncthreads();
    for (int i = t; i < NB; i += PB) {
        const int h = hist[i];
        lcur[i] = h > 0 ? atomicAdd(&gcount[i], h) : 0;
    }
    __syncthreads();
    for (int j = 0; j < cnt; ++j) {
        const unsigned p = pa[j];
        const unsigned b = p >> 23;
        const int pos = atomicAdd(&lcur[b], 1);
        gEdges[b * CAP + pos] = p & 0x7FFFFFu; // strip bucket bits
    }
    // block min/max reduction -> 2 global atomics
#pragma unroll
    for (int m = 32; m >= 1; m >>= 1) {
        kmin = min(kmin, __shfl_xor(kmin, m));
        kmax = max(kmax, __shfl_xor(kmax, m));
    }
    const int wave = t >> 6;
    if ((t & 63) == 0) { smn[wave] = kmin; smx[wave] = kmax; }
    __syncthreads();
    if (t == 0) {
#pragma unroll
        for (int w = 1; w < PB / 64; ++w) {
            kmin = min(kmin, smn[w]);
            kmax = max(kmax, smx[w]);
        }
        atomicMin(&minmax[0], kmin);
        atomicMax(&minmax[1], kmax);
    }
}

// Kernel C: one block per bucket. Accumulate 98 rows x 32 dims in LDS with
// LDS float atomics, recomputing w = exp(minmaxnorm(leaky(s0+s1))), then
// write out = acc/wsum once. No global fp32 atomics anywhere.
__global__ __launch_bounds__(256) void k_bucket(const int* __restrict__ gcount,
                                                const unsigned* __restrict__ gEdges,
                                                const float* __restrict__ s0,
                                                const float* __restrict__ s1,
                                                const float* __restrict__ Xp,
                                                const int* __restrict__ minmax,
                                                float* __restrict__ out) {
    __shared__ float acc[RPB * D_OUT]; // 12.25 KiB
    __shared__ float wsum[RPB];
    __shared__ float s0l[RPB];
    const int b = blockIdx.x;
    const int r0 = b * RPB;
    const int t = threadIdx.x;
    for (int i = t; i < RPB * D_OUT; i += 256) acc[i] = 0.f;
    for (int i = t; i < RPB; i += 256) {
        wsum[i] = 0.f;
        const int r = r0 + i;
        s0l[i] = (r < N_NODES) ? s0[r] : 0.f;
    }
    __syncthreads();
    const float mn = dec_f(minmax[0]);
    const float mx = dec_f(minmax[1]);
    const float inv = 1.0f / (mx - mn);
    const int cnt = gcount[b];
    const int g = t >> 5;  // 8 edge-groups per block
    const int d = t & 31;  // output dim
    for (int i = g; i < cnt; i += 8) {
        const unsigned p = gEdges[b * CAP + i];
        const unsigned lr = (p >> 16) & 0x7Fu;
        const unsigned c = p & 0xFFFFu;
        float a = s0l[lr] + s1[c];
        a = a > 0.f ? a : ALPHA * a;
        const float w = __expf((a - mn) * inv);
        atomicAdd(&acc[lr * D_OUT + d], w * Xp[(size_t)c * D_OUT + d]);
        if (d == 0) atomicAdd(&wsum[lr], w);
    }
    __syncthreads();
    for (int i = t; i < RPB * D_OUT; i += 256) {
        const int r = r0 + (i >> 5);
        if (r < N_NODES) out[(size_t)r * D_OUT + (i & 31)] = acc[i] / wsum[i >> 5];
    }
}

extern "C" void kernel_launch(void* const* d_in, const int* in_sizes, int n_in,
                              void* d_out, int out_size, void* d_ws, size_t ws_size,
                              hipStream_t stream) {
    const float* X  = (const float*)d_in[0];
    const float* W  = (const float*)d_in[1];
    const float* a0 = (const float*)d_in[2];
    const float* a1 = (const float*)d_in[3];
    const int* row  = (const int*)d_in[4];
    const int* col  = (const int*)d_in[5];
    float* out = (float*)d_out;

    // Workspace layout (4B units):
    // [minmax: 64][gcount: 512][s0: 50048][s1: 50048][Xp: 1.6M][gEdges: NB*CAP]
    float* ws = (float*)d_ws;
    int*      minmax = (int*)ws;
    int*      gcount = (int*)(ws + 64);
    float*    s0 = ws + 64 + NB;
    float*    s1 = s0 + 50048;
    float*    Xp = s1 + 50048;
    unsigned* gEdges = (unsigned*)(Xp + (size_t)N_NODES * D_OUT);

    k_xw<<<N_NODES / 8, 256, 0, stream>>>(X, W, a0, a1, Xp, s0, s1, minmax, gcount);
    k_part<<<(N_EDGES + EB - 1) / EB, PB, 0, stream>>>(row, col, s0, s1, gcount,
                                                       minmax, gEdges);
    k_bucket<<<NB, 256, 0, stream>>>(gcount, gEdges, s0, s1, Xp, minmax, out);
}

// Round 4
// 424.664 us; speedup vs baseline: 1.0345x; 1.0345x over previous
//
#include <hip/hip_runtime.h>
#include <math.h>

#define N_NODES 50000
#define N_EDGES 1600000
#define D_IN 128
#define D_OUT 32
#define ALPHA 0.2f

#define NB  2000     // buckets (NB * RPB == N_NODES exactly)
#define RPB 25       // rows per bucket
#define CAP 1024     // slots per bucket (mean 800, sigma ~28 -> 8 sigma margin)
#define PT  16       // edges per thread in k_part
#define PB  1024     // threads per block in k_part
#define EB  (PT * PB) // 16384 edges per block

// Monotone float<->int key (involution). Works with signed atomicMin/Max.
__device__ __forceinline__ int enc_f(float x) {
    int i = __float_as_int(x);
    return i >= 0 ? i : (i ^ 0x7fffffff);
}
__device__ __forceinline__ float dec_f(int k) {
    return __int_as_float(k >= 0 ? k : (k ^ 0x7fffffff));
}

// Kernel A: X_prime = X @ W  [N,32], s0 = Xp.a0, s1 = Xp.a1.
// 8 nodes per 256-thread block; 32 lanes per node (one per output dim).
// Block 0 also zeroes the bucket counters + minmax slots (stream-ordered).
__global__ __launch_bounds__(256) void k_xw(const float* __restrict__ X,
                                            const float* __restrict__ W,
                                            const float* __restrict__ a0,
                                            const float* __restrict__ a1,
                                            float* __restrict__ Xp,
                                            float* __restrict__ s0,
                                            float* __restrict__ s1,
                                            int* __restrict__ minmax,
                                            int* __restrict__ gcount) {
    __shared__ float Wl[D_IN * D_OUT]; // 16 KiB
    __shared__ float Xl[8 * D_IN];     // 4 KiB
    const int tid = threadIdx.x;
    if (blockIdx.x == 0) {
        if (tid == 0) {
            minmax[0] = 0x7fffffff; // running min key
            minmax[1] = 0x80000000; // running max key
        }
        for (int i = tid; i < NB; i += 256) gcount[i] = 0;
    }
    for (int i = tid; i < D_IN * D_OUT; i += 256) Wl[i] = W[i];
    const int node0 = blockIdx.x * 8; // 50000/8 = 6250 blocks, no tail
    for (int i = tid; i < 8 * D_IN; i += 256) Xl[i] = X[(size_t)node0 * D_IN + i];
    __syncthreads();

    const int g = tid >> 5;   // node group within block
    const int t = tid & 31;   // output dim
    const int node = node0 + g;
    const float* xr = &Xl[g * D_IN];
    float acc = 0.f;
#pragma unroll
    for (int k = 0; k < D_IN; ++k) acc += xr[k] * Wl[k * D_OUT + t];
    Xp[(size_t)node * D_OUT + t] = acc;

    float v0 = acc * a0[t];
    float v1 = acc * a1[t];
#pragma unroll
    for (int m = 16; m >= 1; m >>= 1) {
        v0 += __shfl_xor(v0, m);
        v1 += __shfl_xor(v1, m);
    }
    if (t == 0) { s0[node] = v0; s1[node] = v1; }
}

// Kernel B: bucket-partition edges + global min/max.
// Per block: LDS histogram over NB buckets -> one global atomicAdd per
// bucket reserves a contiguous range in that bucket's fixed region ->
// 8B entries {lr<<16|col, leaky_score} written in per-block bursts
// (~8 entries = 64B per bucket per block -> line-batched from one XCD).
__global__ __launch_bounds__(PB) void k_part(const int* __restrict__ row,
                                             const int* __restrict__ col,
                                             const float* __restrict__ s0,
                                             const float* __restrict__ s1,
                                             int* __restrict__ gcount,
                                             int* __restrict__ minmax,
                                             uint2* __restrict__ gEdges) {
    __shared__ int hist[NB]; // 8 KB
    __shared__ int lcur[NB]; // 8 KB
    __shared__ int smn[PB / 64], smx[PB / 64];
    const int t = threadIdx.x;
    for (int i = t; i < NB; i += PB) hist[i] = 0;
    __syncthreads();

    const int base = blockIdx.x * EB;
    unsigned px[PT]; // (b:11 | lr:5 | col:16)
    float    fa[PT]; // leaky-relu'd score
    int cnt = 0;
    int kmin = 0x7fffffff, kmax = 0x80000000;
#pragma unroll
    for (int i = 0; i < PT; ++i) {
        const int e = base + i * PB + t;
        if (e >= N_EDGES) break; // e increases with i
        const int r = row[e];
        const int c = col[e];
        float a = s0[r] + s1[c];
        a = a > 0.f ? a : ALPHA * a;
        const int k = enc_f(a);
        kmin = min(kmin, k);
        kmax = max(kmax, k);
        const unsigned b = (unsigned)r / RPB;
        const unsigned lr = (unsigned)r - b * RPB;
        px[cnt] = (b << 21) | (lr << 16) | (unsigned)c;
        fa[cnt] = a;
        ++cnt;
        atomicAdd(&hist[b], 1);
    }
    __syncthreads();
    for (int i = t; i < NB; i += PB) {
        const int h = hist[i];
        lcur[i] = h > 0 ? atomicAdd(&gcount[i], h) : 0;
    }
    __syncthreads();
    for (int j = 0; j < cnt; ++j) {
        const unsigned p = px[j];
        const unsigned b = p >> 21;
        const int pos = atomicAdd(&lcur[b], 1);
        gEdges[(size_t)b * CAP + pos] =
            make_uint2(p & 0x1FFFFFu, (unsigned)__float_as_int(fa[j]));
    }
    // block min/max reduction -> 2 global atomics
#pragma unroll
    for (int m = 32; m >= 1; m >>= 1) {
        kmin = min(kmin, __shfl_xor(kmin, m));
        kmax = max(kmax, __shfl_xor(kmax, m));
    }
    const int wave = t >> 6;
    if ((t & 63) == 0) { smn[wave] = kmin; smx[wave] = kmax; }
    __syncthreads();
    if (t == 0) {
#pragma unroll
        for (int w = 1; w < PB / 64; ++w) {
            kmin = min(kmin, smn[w]);
            kmax = max(kmax, smx[w]);
        }
        atomicMin(&minmax[0], kmin);
        atomicMax(&minmax[1], kmax);
    }
}

// Kernel C: one block per bucket (2000 blocks). Accumulate 25 rows x 32 dims
// in LDS with LDS float atomics; 8 edge-groups of 32 lanes, 4-way software
// pipeline keeps 4 independent Xp gathers in flight per group.
__global__ __launch_bounds__(256, 8) void k_bucket(const int* __restrict__ gcount,
                                                   const uint2* __restrict__ gEdges,
                                                   const float* __restrict__ Xp,
                                                   const int* __restrict__ minmax,
                                                   float* __restrict__ out) {
    __shared__ float acc[RPB * D_OUT]; // 3.2 KB
    __shared__ float wsum[RPB];
    const int b = blockIdx.x;
    const int t = threadIdx.x;
    for (int i = t; i < RPB * D_OUT; i += 256) acc[i] = 0.f;
    if (t < RPB) wsum[t] = 0.f;
    __syncthreads();
    const float mn = dec_f(minmax[0]);
    const float mx = dec_f(minmax[1]);
    const float inv = 1.0f / (mx - mn);
    const int cnt = gcount[b];
    const int g = t >> 5;  // edge-group (8 per block)
    const int d = t & 31;  // output dim
    const uint2* eb = gEdges + (size_t)b * CAP;
    int i = g;
    for (; i + 24 < cnt; i += 32) {
        const uint2 e0 = eb[i];
        const uint2 e1 = eb[i + 8];
        const uint2 e2 = eb[i + 16];
        const uint2 e3 = eb[i + 24];
        const float x0 = Xp[(size_t)(e0.x & 0xFFFFu) * D_OUT + d];
        const float x1 = Xp[(size_t)(e1.x & 0xFFFFu) * D_OUT + d];
        const float x2 = Xp[(size_t)(e2.x & 0xFFFFu) * D_OUT + d];
        const float x3 = Xp[(size_t)(e3.x & 0xFFFFu) * D_OUT + d];
        const float w0 = __expf((__int_as_float(e0.y) - mn) * inv);
        const float w1 = __expf((__int_as_float(e1.y) - mn) * inv);
        const float w2 = __expf((__int_as_float(e2.y) - mn) * inv);
        const float w3 = __expf((__int_as_float(e3.y) - mn) * inv);
        atomicAdd(&acc[(e0.x >> 16) * D_OUT + d], w0 * x0);
        atomicAdd(&acc[(e1.x >> 16) * D_OUT + d], w1 * x1);
        atomicAdd(&acc[(e2.x >> 16) * D_OUT + d], w2 * x2);
        atomicAdd(&acc[(e3.x >> 16) * D_OUT + d], w3 * x3);
        if (d == 0) {
            atomicAdd(&wsum[e0.x >> 16], w0);
            atomicAdd(&wsum[e1.x >> 16], w1);
            atomicAdd(&wsum[e2.x >> 16], w2);
            atomicAdd(&wsum[e3.x >> 16], w3);
        }
    }
    for (; i < cnt; i += 8) {
        const uint2 e0 = eb[i];
        const float x0 = Xp[(size_t)(e0.x & 0xFFFFu) * D_OUT + d];
        const float w0 = __expf((__int_as_float(e0.y) - mn) * inv);
        atomicAdd(&acc[(e0.x >> 16) * D_OUT + d], w0 * x0);
        if (d == 0) atomicAdd(&wsum[e0.x >> 16], w0);
    }
    __syncthreads();
    // NB*RPB == N_NODES exactly -> no row guard needed
    const int r0 = b * RPB;
    for (int i2 = t; i2 < RPB * D_OUT; i2 += 256) {
        out[(size_t)r0 * D_OUT + i2] = acc[i2] / wsum[i2 >> 5];
    }
}

extern "C" void kernel_launch(void* const* d_in, const int* in_sizes, int n_in,
                              void* d_out, int out_size, void* d_ws, size_t ws_size,
                              hipStream_t stream) {
    const float* X  = (const float*)d_in[0];
    const float* W  = (const float*)d_in[1];
    const float* a0 = (const float*)d_in[2];
    const float* a1 = (const float*)d_in[3];
    const int* row  = (const int*)d_in[4];
    const int* col  = (const int*)d_in[5];
    float* out = (float*)d_out;

    // Workspace layout (4B units):
    // [minmax: 64][gcount: 2048][s0: 50048][s1: 50048][Xp: 1.6M][gEdges: NB*CAP uint2]
    float* ws = (float*)d_ws;
    int*   minmax = (int*)ws;
    int*   gcount = (int*)(ws + 64);
    float* s0 = ws + 64 + 2048;
    float* s1 = s0 + 50048;
    float* Xp = s1 + 50048;
    uint2* gEdges = (uint2*)(Xp + (size_t)N_NODES * D_OUT); // 8B-aligned offset

    k_xw<<<N_NODES / 8, 256, 0, stream>>>(X, W, a0, a1, Xp, s0, s1, minmax, gcount);
    k_part<<<(N_EDGES + EB - 1) / EB, PB, 0, stream>>>(row, col, s0, s1, gcount,
                                                       minmax, gEdges);
    k_bucket<<<NB, 256, 0, stream>>>(gcount, gEdges, Xp, minmax, out);
}